// Round 1
// 1403.236 us; speedup vs baseline: 1.5323x; 1.5323x over previous
//
#include <hip/hip_runtime.h>
#include <stdint.h>

#define NB 8192
#define DIM 512

typedef __bf16 bf16x8 __attribute__((ext_vector_type(8)));
typedef float f32x4 __attribute__((ext_vector_type(4)));

__device__ __forceinline__ unsigned short f2bf(float x) {
  union { float f; unsigned u; } v; v.f = x;
  unsigned r = v.u + 0x7fff + ((v.u >> 16) & 1);
  return (unsigned short)(r >> 16);
}

// ---------------- prep: bf16 copy of rows + fp64 norm ----------------
__global__ __launch_bounds__(256)
void k_prep(const float* __restrict__ g, unsigned short* __restrict__ gb,
            float* __restrict__ rinvF, double* __restrict__ normD) {
  const int row = blockIdx.x;
  const int t = threadIdx.x;                 // 256 threads, 2 elems each
  const float2 v = ((const float2*)(g + (size_t)row * DIM))[t];
  ushort2 b; b.x = f2bf(v.x); b.y = f2bf(v.y);
  ((ushort2*)(gb + (size_t)row * DIM))[t] = b;
  double ss = (double)v.x * v.x + (double)v.y * v.y;
#pragma unroll
  for (int o = 32; o; o >>= 1) ss += __shfl_down(ss, o, 64);
  __shared__ double l[4];
  if ((t & 63) == 0) l[t >> 6] = ss;
  __syncthreads();
  if (t == 0) {
    double n = sqrt(l[0] + l[1] + l[2] + l[3]);
    if (n < 1e-12) n = 1e-12;
    normD[row] = n;
    rinvF[row] = (float)(1.0 / n);
  }
}

__global__ __launch_bounds__(256)
void k_cast(const float* __restrict__ s, unsigned short* __restrict__ d, int npairs) {
  int i = blockIdx.x * 256 + threadIdx.x;
  if (i < npairs) {
    float2 v = ((const float2*)s)[i];
    ushort2 b; b.x = f2bf(v.x); b.y = f2bf(v.y);
    ((ushort2*)d)[i] = b;
  }
}

// ---------------- bf16 GEMM, C = A @ B^T (A: MxK, B: NxK row-major) ----------------
template <bool SCALED>
__global__ __launch_bounds__(256, 2)
void k_gemm_bt(const unsigned short* __restrict__ A, const unsigned short* __restrict__ Bm,
               float* __restrict__ C, int M, int N, int K,
               const float* __restrict__ rowScale, const float* __restrict__ colScale,
               float mul) {
  __shared__ __align__(16) unsigned short lA[128 * 32];
  __shared__ __align__(16) unsigned short lB[128 * 32];
  const int tid = threadIdx.x;
  const int lane = tid & 63;
  const int wave = tid >> 6;
  const long brow = (long)blockIdx.y * 128;
  const long bcol = (long)blockIdx.x * 128;
  const int wrow = (wave >> 1) * 64;
  const int wcol = (wave & 1) * 64;

  f32x4 acc[4][4];
#pragma unroll
  for (int i = 0; i < 4; ++i)
#pragma unroll
    for (int j = 0; j < 4; ++j) acc[i][j] = (f32x4){0.f, 0.f, 0.f, 0.f};

  const int c0 = tid, c1 = tid + 256;
  const size_t aoff0 = (size_t)(brow + (c0 >> 2)) * K + (size_t)((c0 & 3) * 8);
  const size_t aoff1 = (size_t)(brow + (c1 >> 2)) * K + (size_t)((c1 & 3) * 8);
  const size_t boff0 = (size_t)(bcol + (c0 >> 2)) * K + (size_t)((c0 & 3) * 8);
  const size_t boff1 = (size_t)(bcol + (c1 >> 2)) * K + (size_t)((c1 & 3) * 8);

  for (int kb = 0; kb < K; kb += 32) {
    __builtin_amdgcn_global_load_lds(
        (const __attribute__((address_space(1))) void*)(A + aoff0 + kb),
        (__attribute__((address_space(3))) void*)(lA + c0 * 8), 16, 0, 0);
    __builtin_amdgcn_global_load_lds(
        (const __attribute__((address_space(1))) void*)(A + aoff1 + kb),
        (__attribute__((address_space(3))) void*)(lA + c1 * 8), 16, 0, 0);
    __builtin_amdgcn_global_load_lds(
        (const __attribute__((address_space(1))) void*)(Bm + boff0 + kb),
        (__attribute__((address_space(3))) void*)(lB + c0 * 8), 16, 0, 0);
    __builtin_amdgcn_global_load_lds(
        (const __attribute__((address_space(1))) void*)(Bm + boff1 + kb),
        (__attribute__((address_space(3))) void*)(lB + c1 * 8), 16, 0, 0);
    __syncthreads();

    const int fr = lane & 15;
    const int fk = (lane >> 4) * 8;
    bf16x8 af[4], bfr[4];
#pragma unroll
    for (int i = 0; i < 4; ++i)
      af[i] = *(const bf16x8*)(lA + (wrow + i * 16 + fr) * 32 + fk);
#pragma unroll
    for (int j = 0; j < 4; ++j)
      bfr[j] = *(const bf16x8*)(lB + (wcol + j * 16 + fr) * 32 + fk);
#pragma unroll
    for (int i = 0; i < 4; ++i)
#pragma unroll
      for (int j = 0; j < 4; ++j)
        acc[i][j] = __builtin_amdgcn_mfma_f32_16x16x32_bf16(af[i], bfr[j], acc[i][j], 0, 0, 0);
    __syncthreads();
  }

  const int lr = (lane >> 4) * 4;
  const int lc = lane & 15;
#pragma unroll
  for (int j = 0; j < 4; ++j) {
    const long gc = bcol + wcol + j * 16 + lc;
    float cs = mul;
    if (SCALED) cs *= colScale[gc];
#pragma unroll
    for (int i = 0; i < 4; ++i) {
      const long gr0 = brow + wrow + i * 16 + lr;
#pragma unroll
      for (int v = 0; v < 4; ++v) {
        const long gr = gr0 + v;
        float sc = cs;
        if (SCALED) sc *= rowScale[gr];
        C[(size_t)gr * N + gc] = acc[i][j][v] * sc;
      }
    }
  }
}

// ---------------- top-k helpers ----------------
template <int K>
__device__ __forceinline__ void topk_insert(float (&v)[K], int (&id)[K], float x, int ix) {
  if (x > v[K - 1]) {
    float nv = x; int ni = ix;
#pragma unroll
    for (int p = 0; p < K; ++p) {
      if (nv > v[p]) {
        float tv = v[p]; v[p] = nv; nv = tv;
        int ti = id[p]; id[p] = ni; ni = ti;
      }
    }
  }
}

// ---------------- row candidate top-16 (one block per row) ----------------
// Threshold-then-compact, exact:
//   T = 16th-largest of the 256 per-thread maxima. T is an element of the row,
//   and T <= s16 (else >=16 elements would exceed s16). So {x >= T} contains the
//   exact top-16; compact those (~16-30 survivors) and rank-order them with the
//   SAME total order as before (value desc, index asc) -> identical output set.
__global__ __launch_bounds__(256)
void k_cand_rows(const float* __restrict__ S, int* __restrict__ candOut) {
  const int row = blockIdx.x;
  const float4* sr4 = (const float4*)(S + (size_t)row * NB);
  const int t = threadIdx.x;

  // pass 1: read 32 elements (8 x float4) into registers, running max
  float4 r[8];
  float m = -1e30f;
#pragma unroll
  for (int i = 0; i < 8; ++i) {
    r[i] = sr4[t + 256 * i];
    m = fmaxf(m, fmaxf(fmaxf(r[i].x, r[i].y), fmaxf(r[i].z, r[i].w)));
  }

  __shared__ float sm[256];
  sm[t] = m;
  __syncthreads();

  // rank my max among the 256 maxima (broadcast LDS reads, conflict-free)
  int rank = 0;
#pragma unroll 8
  for (int j = 0; j < 256; ++j) {
    const float v = sm[j];
    rank += (v > m || (v == m && j < t)) ? 1 : 0;
  }
  __shared__ float sT;
  if (rank == 15) sT = m;   // exactly one thread has rank 15
  __syncthreads();
  const float T = sT;

  // pass 2: compact survivors (from registers; no re-read)
  __shared__ int cnt;
  __shared__ float cv[256];
  __shared__ int ci[256];
  if (t == 0) cnt = 0;
  __syncthreads();
#pragma unroll
  for (int i = 0; i < 8; ++i) {
    const int bi = (t + 256 * i) * 4;
    if (r[i].x >= T) { int p = atomicAdd(&cnt, 1); if (p < 256) { cv[p] = r[i].x; ci[p] = bi; } }
    if (r[i].y >= T) { int p = atomicAdd(&cnt, 1); if (p < 256) { cv[p] = r[i].y; ci[p] = bi + 1; } }
    if (r[i].z >= T) { int p = atomicAdd(&cnt, 1); if (p < 256) { cv[p] = r[i].z; ci[p] = bi + 2; } }
    if (r[i].w >= T) { int p = atomicAdd(&cnt, 1); if (p < 256) { cv[p] = r[i].w; ci[p] = bi + 3; } }
  }
  __syncthreads();
  const int n = min(cnt, 256);

  // final: rank survivors with the exact old total order; emit ranks 0..15.
  // n >= 16 guaranteed (the 16 threshold-defining maxima are distinct elements >= T).
  if (t < n) {
    const float mv = cv[t];
    const int mi = ci[t];
    int rk = 0;
    for (int q = 0; q < n; ++q) {
      rk += (cv[q] > mv || (cv[q] == mv && ci[q] < mi)) ? 1 : 0;
    }
    if (rk < 16) candOut[row * 16 + rk] = mi;
  }
}

// ---------------- column candidates: chunked partial top-8 + merge to 16 ----------------
__global__ __launch_bounds__(256)
void k_topk_cols_part(const float* __restrict__ S, float* __restrict__ candV,
                      int* __restrict__ candI) {
  const int col = blockIdx.x * 256 + threadIdx.x;
  const int chunk = blockIdx.y;               // 8 chunks of 1024 rows
  const int r0 = chunk * 1024;
  float v[8]; int id[8];
#pragma unroll
  for (int i = 0; i < 8; ++i) { v[i] = -1e30f; id[i] = -1; }
  const float* p = S + (size_t)r0 * NB + col;
#pragma unroll 4
  for (int i = 0; i < 1024; ++i) topk_insert<8>(v, id, p[(size_t)i * NB], r0 + i);
  const size_t base = ((size_t)col * 8 + chunk) * 8;
#pragma unroll
  for (int i = 0; i < 8; ++i) { candV[base + i] = v[i]; candI[base + i] = id[i]; }
}

__global__ __launch_bounds__(256)
void k_cand_cols(const float* __restrict__ candV, const int* __restrict__ candI,
                 int* __restrict__ candOut) {
  const int col = blockIdx.x * 256 + threadIdx.x;
  float v[16]; int id[16];
#pragma unroll
  for (int i = 0; i < 16; ++i) { v[i] = -1e30f; id[i] = -1; }
  const size_t base = (size_t)col * 64;
  for (int c = 0; c < 64; ++c) topk_insert<16>(v, id, candV[base + c], candI[base + c]);
#pragma unroll
  for (int i = 0; i < 16; ++i) candOut[col * 16 + i] = id[i];
}

// ---------------- exact fp64 rescore of 16 candidates -> top-8 + softmax ----------------
__global__ __launch_bounds__(256)
void k_rescore(const float* __restrict__ Xq, const float* __restrict__ Xc,
               const double* __restrict__ nQ, const double* __restrict__ nC,
               const int* __restrict__ cand, int* __restrict__ idxOut,
               float* __restrict__ wOut) {
  const int r = blockIdx.x;
  const int t = threadIdx.x;
  __shared__ float q[DIM];
  __shared__ double sc[16];
  __shared__ int sidx[16];
  const float2 qv = ((const float2*)(Xq + (size_t)r * DIM))[t];
  q[2 * t] = qv.x; q[2 * t + 1] = qv.y;
  if (t < 16) sidx[t] = cand[r * 16 + t];
  __syncthreads();
  const int wave = t >> 6, lane = t & 63;
  for (int c = wave; c < 16; c += 4) {
    const float* xr = Xc + (size_t)sidx[c] * DIM;
    double acc = 0.0;
    for (int j = lane; j < DIM; j += 64) acc += (double)q[j] * (double)xr[j];
#pragma unroll
    for (int o = 32; o; o >>= 1) acc += __shfl_down(acc, o, 64);
    if (lane == 0) sc[c] = acc;
  }
  __syncthreads();
  if (t == 0) {
    const double nq = nQ[r];
    double s[16]; int id[16];
#pragma unroll
    for (int i = 0; i < 16; ++i) {
      id[i] = sidx[i];
      s[i] = sc[i] / (nq * nC[sidx[i]]) * 5.0;   // /tau, tau=0.2
    }
    // insertion sort: descending score, ascending index on ties
    for (int i = 1; i < 16; ++i) {
      double sv = s[i]; int iv = id[i]; int j = i - 1;
      while (j >= 0 && (s[j] < sv || (s[j] == sv && id[j] > iv))) {
        s[j + 1] = s[j]; id[j + 1] = id[j]; --j;
      }
      s[j + 1] = sv; id[j + 1] = iv;
    }
    double m = s[0], e[8], sum = 0.0;
#pragma unroll
    for (int i = 0; i < 8; ++i) { e[i] = exp(s[i] - m); sum += e[i]; }
    const double inv = 1.0 / sum;
#pragma unroll
    for (int i = 0; i < 8; ++i) {
      idxOut[r * 8 + i] = id[i];
      wOut[r * 8 + i] = (float)(e[i] * inv);
    }
  }
}

// ---------------- gather message + residual + LayerNorm ----------------
__global__ __launch_bounds__(256)
void k_msg_ln(const float* __restrict__ g, const float* __restrict__ P,
              const int* __restrict__ idx, const float* __restrict__ w,
              const float* __restrict__ gamma, const float* __restrict__ beta,
              float* __restrict__ out) {
  const int row = blockIdx.x;
  const int t = threadIdx.x;                  // 256 threads, 2 elems each
  __shared__ int sidx[8];
  __shared__ float sw[8];
  if (t < 8) { sidx[t] = idx[row * 8 + t]; sw[t] = w[row * 8 + t]; }
  __syncthreads();
  float mx = 0.f, my = 0.f;
#pragma unroll
  for (int k = 0; k < 8; ++k) {
    const float2 pv = ((const float2*)(P + (size_t)sidx[k] * DIM))[t];
    mx += sw[k] * pv.x; my += sw[k] * pv.y;
  }
  const float2 gv = ((const float2*)(g + (size_t)row * DIM))[t];
  const float x0 = gv.x + 0.3f * mx;
  const float x1 = gv.y + 0.3f * my;
  float s = x0 + x1, ss = x0 * x0 + x1 * x1;
#pragma unroll
  for (int o = 32; o; o >>= 1) { s += __shfl_down(s, o, 64); ss += __shfl_down(ss, o, 64); }
  __shared__ float ls[4], lss[4];
  if ((t & 63) == 0) { ls[t >> 6] = s; lss[t >> 6] = ss; }
  __syncthreads();
  const float tot = ls[0] + ls[1] + ls[2] + ls[3];
  const float tots = lss[0] + lss[1] + lss[2] + lss[3];
  const float mu = tot * (1.0f / DIM);
  const float var = tots * (1.0f / DIM) - mu * mu;
  const float rstd = rsqrtf(var + 1e-5f);
  const float2 gm = ((const float2*)gamma)[t];
  const float2 bt = ((const float2*)beta)[t];
  float2 o2;
  o2.x = (x0 - mu) * rstd * gm.x + bt.x;
  o2.y = (x1 - mu) * rstd * gm.y + bt.y;
  ((float2*)(out + (size_t)row * DIM))[t] = o2;
}

extern "C" void kernel_launch(void* const* d_in, const int* in_sizes, int n_in,
                              void* d_out, int out_size, void* d_ws, size_t ws_size,
                              hipStream_t stream) {
  const float* gI = (const float*)d_in[0];
  const float* gT = (const float*)d_in[1];
  const float* Wi = (const float*)d_in[2];
  const float* Wt = (const float*)d_in[3];
  const float* gamma_i = (const float*)d_in[4];
  const float* beta_i  = (const float*)d_in[5];
  const float* gamma_t = (const float*)d_in[6];
  const float* beta_t  = (const float*)d_in[7];

  float* outI = (float*)d_out;
  float* outT = outI + (size_t)NB * DIM;
  float* S    = outT + (size_t)NB * DIM;

  // workspace carve-up (byte cursor, 16B aligned)
  char* wsb = (char*)d_ws;
  size_t off = 0;
  auto alloc = [&](size_t bytes) -> void* {
    off = (off + 15) & ~(size_t)15;
    void* p = wsb + off;
    off += bytes;
    return p;
  };
  unsigned short* gIb = (unsigned short*)alloc((size_t)NB * DIM * 2);
  unsigned short* gTb = (unsigned short*)alloc((size_t)NB * DIM * 2);
  unsigned short* Wib = (unsigned short*)alloc((size_t)DIM * DIM * 2);
  unsigned short* Wtb = (unsigned short*)alloc((size_t)DIM * DIM * 2);
  float* rinvI = (float*)alloc((size_t)NB * 4);
  float* rinvT = (float*)alloc((size_t)NB * 4);
  double* normI = (double*)alloc((size_t)NB * 8);
  double* normT = (double*)alloc((size_t)NB * 8);
  float* Pt = (float*)alloc((size_t)NB * DIM * 4);
  float* Pi = (float*)alloc((size_t)NB * DIM * 4);
  float* candV = (float*)alloc((size_t)NB * 64 * 4);
  int*   candI = (int*)alloc((size_t)NB * 64 * 4);
  int*   candRow = (int*)alloc((size_t)NB * 16 * 4);
  int*   candCol = (int*)alloc((size_t)NB * 16 * 4);
  int*   idx_it = (int*)alloc((size_t)NB * 8 * 4);
  float* w_it   = (float*)alloc((size_t)NB * 8 * 4);
  int*   idx_ti = (int*)alloc((size_t)NB * 8 * 4);
  float* w_ti   = (float*)alloc((size_t)NB * 8 * 4);

  k_prep<<<NB, 256, 0, stream>>>(gI, gIb, rinvI, normI);
  k_prep<<<NB, 256, 0, stream>>>(gT, gTb, rinvT, normT);
  k_cast<<<(DIM * DIM / 2 + 255) / 256, 256, 0, stream>>>(Wi, Wib, DIM * DIM / 2);
  k_cast<<<(DIM * DIM / 2 + 255) / 256, 256, 0, stream>>>(Wt, Wtb, DIM * DIM / 2);

  // S = (gi . gt^T)/tau, scaled in epilogue by rinvI[i]*rinvT[j]*5
  k_gemm_bt<true><<<dim3(NB / 128, NB / 128), 256, 0, stream>>>(
      gIb, gTb, S, NB, NB, DIM, rinvI, rinvT, 5.0f);
  // Pt = gT @ Wt^T ; Pi = gI @ Wi^T
  k_gemm_bt<false><<<dim3(DIM / 128, NB / 128), 256, 0, stream>>>(
      gTb, Wtb, Pt, NB, DIM, DIM, nullptr, nullptr, 1.0f);
  k_gemm_bt<false><<<dim3(DIM / 128, NB / 128), 256, 0, stream>>>(
      gIb, Wib, Pi, NB, DIM, DIM, nullptr, nullptr, 1.0f);

  // candidates from bf16 S
  k_cand_rows<<<NB, 256, 0, stream>>>(S, candRow);
  k_topk_cols_part<<<dim3(NB / 256, 8), 256, 0, stream>>>(S, candV, candI);
  k_cand_cols<<<NB / 256, 256, 0, stream>>>(candV, candI, candCol);

  // exact fp64 rescore -> final top-8 + weights
  k_rescore<<<NB, 256, 0, stream>>>(gI, gT, normI, normT, candRow, idx_it, w_it);
  k_rescore<<<NB, 256, 0, stream>>>(gT, gI, normT, normI, candCol, idx_ti, w_ti);

  k_msg_ln<<<NB, 256, 0, stream>>>(gI, Pt, idx_it, w_it, gamma_i, beta_i, outI);
  k_msg_ln<<<NB, 256, 0, stream>>>(gT, Pi, idx_ti, w_ti, gamma_t, beta_t, outT);
}

// Round 2
// 1132.320 us; speedup vs baseline: 1.8989x; 1.2393x over previous
//
#include <hip/hip_runtime.h>
#include <stdint.h>

#define NB 8192
#define DIM 512
#define COL_CHUNKS 32
#define CHUNK_ROWS (NB / COL_CHUNKS)   // 256

typedef __bf16 bf16x8 __attribute__((ext_vector_type(8)));
typedef float f32x4 __attribute__((ext_vector_type(4)));

__device__ __forceinline__ unsigned short f2bf(float x) {
  union { float f; unsigned u; } v; v.f = x;
  unsigned r = v.u + 0x7fff + ((v.u >> 16) & 1);
  return (unsigned short)(r >> 16);
}

// ---------------- prep: bf16 copy of rows + fp64 norm ----------------
__global__ __launch_bounds__(256)
void k_prep(const float* __restrict__ g, unsigned short* __restrict__ gb,
            float* __restrict__ rinvF, double* __restrict__ normD) {
  const int row = blockIdx.x;
  const int t = threadIdx.x;                 // 256 threads, 2 elems each
  const float2 v = ((const float2*)(g + (size_t)row * DIM))[t];
  ushort2 b; b.x = f2bf(v.x); b.y = f2bf(v.y);
  ((ushort2*)(gb + (size_t)row * DIM))[t] = b;
  double ss = (double)v.x * v.x + (double)v.y * v.y;
#pragma unroll
  for (int o = 32; o; o >>= 1) ss += __shfl_down(ss, o, 64);
  __shared__ double l[4];
  if ((t & 63) == 0) l[t >> 6] = ss;
  __syncthreads();
  if (t == 0) {
    double n = sqrt(l[0] + l[1] + l[2] + l[3]);
    if (n < 1e-12) n = 1e-12;
    normD[row] = n;
    rinvF[row] = (float)(1.0 / n);
  }
}

__global__ __launch_bounds__(256)
void k_cast(const float* __restrict__ s, unsigned short* __restrict__ d, int npairs) {
  int i = blockIdx.x * 256 + threadIdx.x;
  if (i < npairs) {
    float2 v = ((const float2*)s)[i];
    ushort2 b; b.x = f2bf(v.x); b.y = f2bf(v.y);
    ((ushort2*)d)[i] = b;
  }
}

// ---------------- bf16 GEMM, C = A @ B^T (A: MxK, B: NxK row-major) ----------------
template <bool SCALED>
__global__ __launch_bounds__(256, 2)
void k_gemm_bt(const unsigned short* __restrict__ A, const unsigned short* __restrict__ Bm,
               float* __restrict__ C, int M, int N, int K,
               const float* __restrict__ rowScale, const float* __restrict__ colScale,
               float mul) {
  __shared__ __align__(16) unsigned short lA[128 * 32];
  __shared__ __align__(16) unsigned short lB[128 * 32];
  const int tid = threadIdx.x;
  const int lane = tid & 63;
  const int wave = tid >> 6;
  const long brow = (long)blockIdx.y * 128;
  const long bcol = (long)blockIdx.x * 128;
  const int wrow = (wave >> 1) * 64;
  const int wcol = (wave & 1) * 64;

  f32x4 acc[4][4];
#pragma unroll
  for (int i = 0; i < 4; ++i)
#pragma unroll
    for (int j = 0; j < 4; ++j) acc[i][j] = (f32x4){0.f, 0.f, 0.f, 0.f};

  const int c0 = tid, c1 = tid + 256;
  const size_t aoff0 = (size_t)(brow + (c0 >> 2)) * K + (size_t)((c0 & 3) * 8);
  const size_t aoff1 = (size_t)(brow + (c1 >> 2)) * K + (size_t)((c1 & 3) * 8);
  const size_t boff0 = (size_t)(bcol + (c0 >> 2)) * K + (size_t)((c0 & 3) * 8);
  const size_t boff1 = (size_t)(bcol + (c1 >> 2)) * K + (size_t)((c1 & 3) * 8);

  for (int kb = 0; kb < K; kb += 32) {
    __builtin_amdgcn_global_load_lds(
        (const __attribute__((address_space(1))) void*)(A + aoff0 + kb),
        (__attribute__((address_space(3))) void*)(lA + c0 * 8), 16, 0, 0);
    __builtin_amdgcn_global_load_lds(
        (const __attribute__((address_space(1))) void*)(A + aoff1 + kb),
        (__attribute__((address_space(3))) void*)(lA + c1 * 8), 16, 0, 0);
    __builtin_amdgcn_global_load_lds(
        (const __attribute__((address_space(1))) void*)(Bm + boff0 + kb),
        (__attribute__((address_space(3))) void*)(lB + c0 * 8), 16, 0, 0);
    __builtin_amdgcn_global_load_lds(
        (const __attribute__((address_space(1))) void*)(Bm + boff1 + kb),
        (__attribute__((address_space(3))) void*)(lB + c1 * 8), 16, 0, 0);
    __syncthreads();

    const int fr = lane & 15;
    const int fk = (lane >> 4) * 8;
    bf16x8 af[4], bfr[4];
#pragma unroll
    for (int i = 0; i < 4; ++i)
      af[i] = *(const bf16x8*)(lA + (wrow + i * 16 + fr) * 32 + fk);
#pragma unroll
    for (int j = 0; j < 4; ++j)
      bfr[j] = *(const bf16x8*)(lB + (wcol + j * 16 + fr) * 32 + fk);
#pragma unroll
    for (int i = 0; i < 4; ++i)
#pragma unroll
      for (int j = 0; j < 4; ++j)
        acc[i][j] = __builtin_amdgcn_mfma_f32_16x16x32_bf16(af[i], bfr[j], acc[i][j], 0, 0, 0);
    __syncthreads();
  }

  const int lr = (lane >> 4) * 4;
  const int lc = lane & 15;
#pragma unroll
  for (int j = 0; j < 4; ++j) {
    const long gc = bcol + wcol + j * 16 + lc;
    float cs = mul;
    if (SCALED) cs *= colScale[gc];
#pragma unroll
    for (int i = 0; i < 4; ++i) {
      const long gr0 = brow + wrow + i * 16 + lr;
#pragma unroll
      for (int v = 0; v < 4; ++v) {
        const long gr = gr0 + v;
        float sc = cs;
        if (SCALED) sc *= rowScale[gr];
        C[(size_t)gr * N + gc] = acc[i][j][v] * sc;
      }
    }
  }
}

// ---------------- top-k helpers ----------------
template <int K>
__device__ __forceinline__ void topk_insert(float (&v)[K], int (&id)[K], float x, int ix) {
  if (x > v[K - 1]) {
    float nv = x; int ni = ix;
#pragma unroll
    for (int p = 0; p < K; ++p) {
      if (nv > v[p]) {
        float tv = v[p]; v[p] = nv; nv = tv;
        int ti = id[p]; id[p] = ni; ni = ti;
      }
    }
  }
}

// ---------------- row candidate top-16 (one block per row) ----------------
// Threshold-then-compact, exact:
//   T = 16th-largest of the 256 per-thread maxima. T is an element of the row,
//   and T <= s16 (else >=16 elements would exceed s16). So {x >= T} contains the
//   exact top-16; compact those (~16-30 survivors) and rank-order them with the
//   SAME total order as before (value desc, index asc) -> identical output set.
__global__ __launch_bounds__(256)
void k_cand_rows(const float* __restrict__ S, int* __restrict__ candOut) {
  const int row = blockIdx.x;
  const float4* sr4 = (const float4*)(S + (size_t)row * NB);
  const int t = threadIdx.x;

  // pass 1: read 32 elements (8 x float4) into registers, running max
  float4 r[8];
  float m = -1e30f;
#pragma unroll
  for (int i = 0; i < 8; ++i) {
    r[i] = sr4[t + 256 * i];
    m = fmaxf(m, fmaxf(fmaxf(r[i].x, r[i].y), fmaxf(r[i].z, r[i].w)));
  }

  __shared__ float sm[256];
  sm[t] = m;
  __syncthreads();

  // rank my max among the 256 maxima (broadcast LDS reads, conflict-free)
  int rank = 0;
#pragma unroll 8
  for (int j = 0; j < 256; ++j) {
    const float v = sm[j];
    rank += (v > m || (v == m && j < t)) ? 1 : 0;
  }
  __shared__ float sT;
  if (rank == 15) sT = m;   // exactly one thread has rank 15
  __syncthreads();
  const float T = sT;

  // pass 2: compact survivors (from registers; no re-read)
  __shared__ int cnt;
  __shared__ float cv[256];
  __shared__ int ci[256];
  if (t == 0) cnt = 0;
  __syncthreads();
#pragma unroll
  for (int i = 0; i < 8; ++i) {
    const int bi = (t + 256 * i) * 4;
    if (r[i].x >= T) { int p = atomicAdd(&cnt, 1); if (p < 256) { cv[p] = r[i].x; ci[p] = bi; } }
    if (r[i].y >= T) { int p = atomicAdd(&cnt, 1); if (p < 256) { cv[p] = r[i].y; ci[p] = bi + 1; } }
    if (r[i].z >= T) { int p = atomicAdd(&cnt, 1); if (p < 256) { cv[p] = r[i].z; ci[p] = bi + 2; } }
    if (r[i].w >= T) { int p = atomicAdd(&cnt, 1); if (p < 256) { cv[p] = r[i].w; ci[p] = bi + 3; } }
  }
  __syncthreads();
  const int n = min(cnt, 256);

  // final: rank survivors with the exact old total order; emit ranks 0..15.
  // n >= 16 guaranteed (the 16 threshold-defining maxima are distinct elements >= T).
  if (t < n) {
    const float mv = cv[t];
    const int mi = ci[t];
    int rk = 0;
    for (int q = 0; q < n; ++q) {
      rk += (cv[q] > mv || (cv[q] == mv && ci[q] < mi)) ? 1 : 0;
    }
    if (rk < 16) candOut[row * 16 + rk] = mi;
  }
}

// ---------------- column candidates: chunked partial top-8 + merge to 16 ----------------
// 32 chunks of 256 rows each -> grid (32, 32) = 1024 blocks = 4 blocks/CU
// (was 8 chunks -> 256 blocks -> 1 block/CU, latency-bound at 9.5% occupancy).
// Layout: candV/candI[chunk][col][8] so the merge reads are fully coalesced.
__global__ __launch_bounds__(256)
void k_topk_cols_part(const float* __restrict__ S, float* __restrict__ candV,
                      int* __restrict__ candI) {
  const int col = blockIdx.x * 256 + threadIdx.x;
  const int chunk = blockIdx.y;
  const int r0 = chunk * CHUNK_ROWS;
  float v[8]; int id[8];
#pragma unroll
  for (int i = 0; i < 8; ++i) { v[i] = -1e30f; id[i] = -1; }
  const float* p = S + (size_t)r0 * NB + col;
#pragma unroll 8
  for (int i = 0; i < CHUNK_ROWS; ++i) topk_insert<8>(v, id, p[(size_t)i * NB], r0 + i);
  const size_t base = ((size_t)chunk * NB + col) * 8;
#pragma unroll
  for (int i = 0; i < 8; ++i) { candV[base + i] = v[i]; candI[base + i] = id[i]; }
}

__global__ __launch_bounds__(256)
void k_cand_cols(const float* __restrict__ candV, const int* __restrict__ candI,
                 int* __restrict__ candOut) {
  const int col = blockIdx.x * 256 + threadIdx.x;
  float v[16]; int id[16];
#pragma unroll
  for (int i = 0; i < 16; ++i) { v[i] = -1e30f; id[i] = -1; }
  for (int c = 0; c < COL_CHUNKS; ++c) {
    const size_t base = ((size_t)c * NB + col) * 8;
    const float4* pv = (const float4*)(candV + base);
    const int4*   pi = (const int4*)(candI + base);
    const float4 a = pv[0], b = pv[1];
    const int4  ia = pi[0], ib = pi[1];
    topk_insert<16>(v, id, a.x, ia.x);
    topk_insert<16>(v, id, a.y, ia.y);
    topk_insert<16>(v, id, a.z, ia.z);
    topk_insert<16>(v, id, a.w, ia.w);
    topk_insert<16>(v, id, b.x, ib.x);
    topk_insert<16>(v, id, b.y, ib.y);
    topk_insert<16>(v, id, b.z, ib.z);
    topk_insert<16>(v, id, b.w, ib.w);
  }
#pragma unroll
  for (int i = 0; i < 16; ++i) candOut[col * 16 + i] = id[i];
}

// ---------------- exact fp64 rescore of 16 candidates -> top-8 + softmax ----------------
__global__ __launch_bounds__(256)
void k_rescore(const float* __restrict__ Xq, const float* __restrict__ Xc,
               const double* __restrict__ nQ, const double* __restrict__ nC,
               const int* __restrict__ cand, int* __restrict__ idxOut,
               float* __restrict__ wOut) {
  const int r = blockIdx.x;
  const int t = threadIdx.x;
  __shared__ float q[DIM];
  __shared__ double sc[16];
  __shared__ int sidx[16];
  const float2 qv = ((const float2*)(Xq + (size_t)r * DIM))[t];
  q[2 * t] = qv.x; q[2 * t + 1] = qv.y;
  if (t < 16) sidx[t] = cand[r * 16 + t];
  __syncthreads();
  const int wave = t >> 6, lane = t & 63;
  for (int c = wave; c < 16; c += 4) {
    const float* xr = Xc + (size_t)sidx[c] * DIM;
    double acc = 0.0;
    for (int j = lane; j < DIM; j += 64) acc += (double)q[j] * (double)xr[j];
#pragma unroll
    for (int o = 32; o; o >>= 1) acc += __shfl_down(acc, o, 64);
    if (lane == 0) sc[c] = acc;
  }
  __syncthreads();
  if (t == 0) {
    const double nq = nQ[r];
    double s[16]; int id[16];
#pragma unroll
    for (int i = 0; i < 16; ++i) {
      id[i] = sidx[i];
      s[i] = sc[i] / (nq * nC[sidx[i]]) * 5.0;   // /tau, tau=0.2
    }
    // insertion sort: descending score, ascending index on ties
    for (int i = 1; i < 16; ++i) {
      double sv = s[i]; int iv = id[i]; int j = i - 1;
      while (j >= 0 && (s[j] < sv || (s[j] == sv && id[j] > iv))) {
        s[j + 1] = s[j]; id[j + 1] = id[j]; --j;
      }
      s[j + 1] = sv; id[j + 1] = iv;
    }
    double m = s[0], e[8], sum = 0.0;
#pragma unroll
    for (int i = 0; i < 8; ++i) { e[i] = exp(s[i] - m); sum += e[i]; }
    const double inv = 1.0 / sum;
#pragma unroll
    for (int i = 0; i < 8; ++i) {
      idxOut[r * 8 + i] = id[i];
      wOut[r * 8 + i] = (float)(e[i] * inv);
    }
  }
}

// ---------------- gather message + residual + LayerNorm ----------------
__global__ __launch_bounds__(256)
void k_msg_ln(const float* __restrict__ g, const float* __restrict__ P,
              const int* __restrict__ idx, const float* __restrict__ w,
              const float* __restrict__ gamma, const float* __restrict__ beta,
              float* __restrict__ out) {
  const int row = blockIdx.x;
  const int t = threadIdx.x;                  // 256 threads, 2 elems each
  __shared__ int sidx[8];
  __shared__ float sw[8];
  if (t < 8) { sidx[t] = idx[row * 8 + t]; sw[t] = w[row * 8 + t]; }
  __syncthreads();
  float mx = 0.f, my = 0.f;
#pragma unroll
  for (int k = 0; k < 8; ++k) {
    const float2 pv = ((const float2*)(P + (size_t)sidx[k] * DIM))[t];
    mx += sw[k] * pv.x; my += sw[k] * pv.y;
  }
  const float2 gv = ((const float2*)(g + (size_t)row * DIM))[t];
  const float x0 = gv.x + 0.3f * mx;
  const float x1 = gv.y + 0.3f * my;
  float s = x0 + x1, ss = x0 * x0 + x1 * x1;
#pragma unroll
  for (int o = 32; o; o >>= 1) { s += __shfl_down(s, o, 64); ss += __shfl_down(ss, o, 64); }
  __shared__ float ls[4], lss[4];
  if ((t & 63) == 0) { ls[t >> 6] = s; lss[t >> 6] = ss; }
  __syncthreads();
  const float tot = ls[0] + ls[1] + ls[2] + ls[3];
  const float tots = lss[0] + lss[1] + lss[2] + lss[3];
  const float mu = tot * (1.0f / DIM);
  const float var = tots * (1.0f / DIM) - mu * mu;
  const float rstd = rsqrtf(var + 1e-5f);
  const float2 gm = ((const float2*)gamma)[t];
  const float2 bt = ((const float2*)beta)[t];
  float2 o2;
  o2.x = (x0 - mu) * rstd * gm.x + bt.x;
  o2.y = (x1 - mu) * rstd * gm.y + bt.y;
  ((float2*)(out + (size_t)row * DIM))[t] = o2;
}

extern "C" void kernel_launch(void* const* d_in, const int* in_sizes, int n_in,
                              void* d_out, int out_size, void* d_ws, size_t ws_size,
                              hipStream_t stream) {
  const float* gI = (const float*)d_in[0];
  const float* gT = (const float*)d_in[1];
  const float* Wi = (const float*)d_in[2];
  const float* Wt = (const float*)d_in[3];
  const float* gamma_i = (const float*)d_in[4];
  const float* beta_i  = (const float*)d_in[5];
  const float* gamma_t = (const float*)d_in[6];
  const float* beta_t  = (const float*)d_in[7];

  float* outI = (float*)d_out;
  float* outT = outI + (size_t)NB * DIM;
  float* S    = outT + (size_t)NB * DIM;

  // workspace carve-up (byte cursor, 16B aligned)
  char* wsb = (char*)d_ws;
  size_t off = 0;
  auto alloc = [&](size_t bytes) -> void* {
    off = (off + 15) & ~(size_t)15;
    void* p = wsb + off;
    off += bytes;
    return p;
  };
  unsigned short* gIb = (unsigned short*)alloc((size_t)NB * DIM * 2);
  unsigned short* gTb = (unsigned short*)alloc((size_t)NB * DIM * 2);
  unsigned short* Wib = (unsigned short*)alloc((size_t)DIM * DIM * 2);
  unsigned short* Wtb = (unsigned short*)alloc((size_t)DIM * DIM * 2);
  float* rinvI = (float*)alloc((size_t)NB * 4);
  float* rinvT = (float*)alloc((size_t)NB * 4);
  double* normI = (double*)alloc((size_t)NB * 8);
  double* normT = (double*)alloc((size_t)NB * 8);
  float* Pt = (float*)alloc((size_t)NB * DIM * 4);
  float* Pi = (float*)alloc((size_t)NB * DIM * 4);
  float* candV = (float*)alloc((size_t)NB * COL_CHUNKS * 8 * 4);
  int*   candI = (int*)alloc((size_t)NB * COL_CHUNKS * 8 * 4);
  int*   candRow = (int*)alloc((size_t)NB * 16 * 4);
  int*   candCol = (int*)alloc((size_t)NB * 16 * 4);
  int*   idx_it = (int*)alloc((size_t)NB * 8 * 4);
  float* w_it   = (float*)alloc((size_t)NB * 8 * 4);
  int*   idx_ti = (int*)alloc((size_t)NB * 8 * 4);
  float* w_ti   = (float*)alloc((size_t)NB * 8 * 4);

  k_prep<<<NB, 256, 0, stream>>>(gI, gIb, rinvI, normI);
  k_prep<<<NB, 256, 0, stream>>>(gT, gTb, rinvT, normT);
  k_cast<<<(DIM * DIM / 2 + 255) / 256, 256, 0, stream>>>(Wi, Wib, DIM * DIM / 2);
  k_cast<<<(DIM * DIM / 2 + 255) / 256, 256, 0, stream>>>(Wt, Wtb, DIM * DIM / 2);

  // S = (gi . gt^T)/tau, scaled in epilogue by rinvI[i]*rinvT[j]*5
  k_gemm_bt<true><<<dim3(NB / 128, NB / 128), 256, 0, stream>>>(
      gIb, gTb, S, NB, NB, DIM, rinvI, rinvT, 5.0f);
  // Pt = gT @ Wt^T ; Pi = gI @ Wi^T
  k_gemm_bt<false><<<dim3(DIM / 128, NB / 128), 256, 0, stream>>>(
      gTb, Wtb, Pt, NB, DIM, DIM, nullptr, nullptr, 1.0f);
  k_gemm_bt<false><<<dim3(DIM / 128, NB / 128), 256, 0, stream>>>(
      gIb, Wib, Pi, NB, DIM, DIM, nullptr, nullptr, 1.0f);

  // candidates from bf16 S
  k_cand_rows<<<NB, 256, 0, stream>>>(S, candRow);
  k_topk_cols_part<<<dim3(NB / 256, COL_CHUNKS), 256, 0, stream>>>(S, candV, candI);
  k_cand_cols<<<NB / 256, 256, 0, stream>>>(candV, candI, candCol);

  // exact fp64 rescore -> final top-8 + weights
  k_rescore<<<NB, 256, 0, stream>>>(gI, gT, normI, normT, candRow, idx_it, w_it);
  k_rescore<<<NB, 256, 0, stream>>>(gT, gI, normT, normI, candCol, idx_ti, w_ti);

  k_msg_ln<<<NB, 256, 0, stream>>>(gI, Pt, idx_it, w_it, gamma_i, beta_i, outI);
  k_msg_ln<<<NB, 256, 0, stream>>>(gT, Pi, idx_ti, w_ti, gamma_t, beta_t, outT);
}

// Round 3
// 1123.780 us; speedup vs baseline: 1.9134x; 1.0076x over previous
//
#include <hip/hip_runtime.h>
#include <stdint.h>

#define NB 8192
#define DIM 512
#define COL_CHUNKS 64
#define CHUNK_ROWS (NB / COL_CHUNKS)   // 128

typedef __bf16 bf16x8 __attribute__((ext_vector_type(8)));
typedef float f32x4 __attribute__((ext_vector_type(4)));

__device__ __forceinline__ unsigned short f2bf(float x) {
  union { float f; unsigned u; } v; v.f = x;
  unsigned r = v.u + 0x7fff + ((v.u >> 16) & 1);
  return (unsigned short)(r >> 16);
}

// ---------------- prep: bf16 copy of rows + fp64 norm ----------------
__global__ __launch_bounds__(256)
void k_prep(const float* __restrict__ g, unsigned short* __restrict__ gb,
            float* __restrict__ rinvF, double* __restrict__ normD) {
  const int row = blockIdx.x;
  const int t = threadIdx.x;                 // 256 threads, 2 elems each
  const float2 v = ((const float2*)(g + (size_t)row * DIM))[t];
  ushort2 b; b.x = f2bf(v.x); b.y = f2bf(v.y);
  ((ushort2*)(gb + (size_t)row * DIM))[t] = b;
  double ss = (double)v.x * v.x + (double)v.y * v.y;
#pragma unroll
  for (int o = 32; o; o >>= 1) ss += __shfl_down(ss, o, 64);
  __shared__ double l[4];
  if ((t & 63) == 0) l[t >> 6] = ss;
  __syncthreads();
  if (t == 0) {
    double n = sqrt(l[0] + l[1] + l[2] + l[3]);
    if (n < 1e-12) n = 1e-12;
    normD[row] = n;
    rinvF[row] = (float)(1.0 / n);
  }
}

__global__ __launch_bounds__(256)
void k_cast(const float* __restrict__ s, unsigned short* __restrict__ d, int npairs) {
  int i = blockIdx.x * 256 + threadIdx.x;
  if (i < npairs) {
    float2 v = ((const float2*)s)[i];
    ushort2 b; b.x = f2bf(v.x); b.y = f2bf(v.y);
    ((ushort2*)d)[i] = b;
  }
}

// ---------------- bf16 GEMM, C = A @ B^T (A: MxK, B: NxK row-major) ----------------
template <bool SCALED>
__global__ __launch_bounds__(256, 2)
void k_gemm_bt(const unsigned short* __restrict__ A, const unsigned short* __restrict__ Bm,
               float* __restrict__ C, int M, int N, int K,
               const float* __restrict__ rowScale, const float* __restrict__ colScale,
               float mul) {
  __shared__ __align__(16) unsigned short lA[128 * 32];
  __shared__ __align__(16) unsigned short lB[128 * 32];
  const int tid = threadIdx.x;
  const int lane = tid & 63;
  const int wave = tid >> 6;
  const long brow = (long)blockIdx.y * 128;
  const long bcol = (long)blockIdx.x * 128;
  const int wrow = (wave >> 1) * 64;
  const int wcol = (wave & 1) * 64;

  f32x4 acc[4][4];
#pragma unroll
  for (int i = 0; i < 4; ++i)
#pragma unroll
    for (int j = 0; j < 4; ++j) acc[i][j] = (f32x4){0.f, 0.f, 0.f, 0.f};

  const int c0 = tid, c1 = tid + 256;
  const size_t aoff0 = (size_t)(brow + (c0 >> 2)) * K + (size_t)((c0 & 3) * 8);
  const size_t aoff1 = (size_t)(brow + (c1 >> 2)) * K + (size_t)((c1 & 3) * 8);
  const size_t boff0 = (size_t)(bcol + (c0 >> 2)) * K + (size_t)((c0 & 3) * 8);
  const size_t boff1 = (size_t)(bcol + (c1 >> 2)) * K + (size_t)((c1 & 3) * 8);

  for (int kb = 0; kb < K; kb += 32) {
    __builtin_amdgcn_global_load_lds(
        (const __attribute__((address_space(1))) void*)(A + aoff0 + kb),
        (__attribute__((address_space(3))) void*)(lA + c0 * 8), 16, 0, 0);
    __builtin_amdgcn_global_load_lds(
        (const __attribute__((address_space(1))) void*)(A + aoff1 + kb),
        (__attribute__((address_space(3))) void*)(lA + c1 * 8), 16, 0, 0);
    __builtin_amdgcn_global_load_lds(
        (const __attribute__((address_space(1))) void*)(Bm + boff0 + kb),
        (__attribute__((address_space(3))) void*)(lB + c0 * 8), 16, 0, 0);
    __builtin_amdgcn_global_load_lds(
        (const __attribute__((address_space(1))) void*)(Bm + boff1 + kb),
        (__attribute__((address_space(3))) void*)(lB + c1 * 8), 16, 0, 0);
    __syncthreads();

    const int fr = lane & 15;
    const int fk = (lane >> 4) * 8;
    bf16x8 af[4], bfr[4];
#pragma unroll
    for (int i = 0; i < 4; ++i)
      af[i] = *(const bf16x8*)(lA + (wrow + i * 16 + fr) * 32 + fk);
#pragma unroll
    for (int j = 0; j < 4; ++j)
      bfr[j] = *(const bf16x8*)(lB + (wcol + j * 16 + fr) * 32 + fk);
#pragma unroll
    for (int i = 0; i < 4; ++i)
#pragma unroll
      for (int j = 0; j < 4; ++j)
        acc[i][j] = __builtin_amdgcn_mfma_f32_16x16x32_bf16(af[i], bfr[j], acc[i][j], 0, 0, 0);
    __syncthreads();
  }

  const int lr = (lane >> 4) * 4;
  const int lc = lane & 15;
#pragma unroll
  for (int j = 0; j < 4; ++j) {
    const long gc = bcol + wcol + j * 16 + lc;
    float cs = mul;
    if (SCALED) cs *= colScale[gc];
#pragma unroll
    for (int i = 0; i < 4; ++i) {
      const long gr0 = brow + wrow + i * 16 + lr;
#pragma unroll
      for (int v = 0; v < 4; ++v) {
        const long gr = gr0 + v;
        float sc = cs;
        if (SCALED) sc *= rowScale[gr];
        C[(size_t)gr * N + gc] = acc[i][j][v] * sc;
      }
    }
  }
}

// ---------------- top-k helpers ----------------
template <int K>
__device__ __forceinline__ void topk_insert(float (&v)[K], int (&id)[K], float x, int ix) {
  if (x > v[K - 1]) {
    float nv = x; int ni = ix;
#pragma unroll
    for (int p = 0; p < K; ++p) {
      if (nv > v[p]) {
        float tv = v[p]; v[p] = nv; nv = tv;
        int ti = id[p]; id[p] = ni; ni = ti;
      }
    }
  }
}

// ---------------- row candidate top-16 (one block per row) ----------------
// Threshold-then-compact, exact:
//   T = 16th-largest of the 256 per-thread maxima. T is an element of the row,
//   and T <= s16 (else >=16 elements would exceed s16). So {x >= T} contains the
//   exact top-16; compact those (~16-30 survivors) and rank-order them with the
//   SAME total order as before (value desc, index asc) -> identical output set.
__global__ __launch_bounds__(256)
void k_cand_rows(const float* __restrict__ S, int* __restrict__ candOut) {
  const int row = blockIdx.x;
  const float4* sr4 = (const float4*)(S + (size_t)row * NB);
  const int t = threadIdx.x;

  // pass 1: read 32 elements (8 x float4) into registers, running max
  float4 r[8];
  float m = -1e30f;
#pragma unroll
  for (int i = 0; i < 8; ++i) {
    r[i] = sr4[t + 256 * i];
    m = fmaxf(m, fmaxf(fmaxf(r[i].x, r[i].y), fmaxf(r[i].z, r[i].w)));
  }

  __shared__ float sm[256];
  sm[t] = m;
  __syncthreads();

  // rank my max among the 256 maxima (broadcast LDS reads, conflict-free)
  int rank = 0;
#pragma unroll 8
  for (int j = 0; j < 256; ++j) {
    const float v = sm[j];
    rank += (v > m || (v == m && j < t)) ? 1 : 0;
  }
  __shared__ float sT;
  if (rank == 15) sT = m;   // exactly one thread has rank 15
  __syncthreads();
  const float T = sT;

  // pass 2: compact survivors (from registers; no re-read)
  __shared__ int cnt;
  __shared__ float cv[256];
  __shared__ int ci[256];
  if (t == 0) cnt = 0;
  __syncthreads();
#pragma unroll
  for (int i = 0; i < 8; ++i) {
    const int bi = (t + 256 * i) * 4;
    if (r[i].x >= T) { int p = atomicAdd(&cnt, 1); if (p < 256) { cv[p] = r[i].x; ci[p] = bi; } }
    if (r[i].y >= T) { int p = atomicAdd(&cnt, 1); if (p < 256) { cv[p] = r[i].y; ci[p] = bi + 1; } }
    if (r[i].z >= T) { int p = atomicAdd(&cnt, 1); if (p < 256) { cv[p] = r[i].z; ci[p] = bi + 2; } }
    if (r[i].w >= T) { int p = atomicAdd(&cnt, 1); if (p < 256) { cv[p] = r[i].w; ci[p] = bi + 3; } }
  }
  __syncthreads();
  const int n = min(cnt, 256);

  // final: rank survivors with the exact old total order; emit ranks 0..15.
  // n >= 16 guaranteed (the 16 threshold-defining maxima are distinct elements >= T).
  if (t < n) {
    const float mv = cv[t];
    const int mi = ci[t];
    int rk = 0;
    for (int q = 0; q < n; ++q) {
      rk += (cv[q] > mv || (cv[q] == mv && ci[q] < mi)) ? 1 : 0;
    }
    if (rk < 16) candOut[row * 16 + rk] = mi;
  }
}

// ---------------- column candidates: chunked partial top-8 + merge to 16 ----------------
// 64 chunks of 128 rows each -> grid (32, 64) = 2048 blocks = 8 blocks/CU =
// 32 waves/CU (was 4 blocks/CU, latency-bound at 34% occupancy).
// Layout: candV/candI[col][chunk][8] so the merge reads are contiguous per thread.
__global__ __launch_bounds__(256)
void k_topk_cols_part(const float* __restrict__ S, float* __restrict__ candV,
                      int* __restrict__ candI) {
  const int col = blockIdx.x * 256 + threadIdx.x;
  const int chunk = blockIdx.y;
  const int r0 = chunk * CHUNK_ROWS;
  float v[8]; int id[8];
#pragma unroll
  for (int i = 0; i < 8; ++i) { v[i] = -1e30f; id[i] = -1; }
  const float* p = S + (size_t)r0 * NB + col;
#pragma unroll 8
  for (int i = 0; i < CHUNK_ROWS; ++i) topk_insert<8>(v, id, p[(size_t)i * NB], r0 + i);
  const size_t base = ((size_t)col * COL_CHUNKS + chunk) * 8;
  ((float4*)(candV + base))[0] = (float4){v[0], v[1], v[2], v[3]};
  ((float4*)(candV + base))[1] = (float4){v[4], v[5], v[6], v[7]};
  ((int4*)(candI + base))[0] = (int4){id[0], id[1], id[2], id[3]};
  ((int4*)(candI + base))[1] = (int4){id[4], id[5], id[6], id[7]};
}

// 64 columns per block, 4 threads per column; each thread merges 16 chunks
// (contiguous 512B read), then LDS rank-merge of the 4x16=64 finalists with
// the exact (val desc, id asc) total order -> top-16 per column.
__global__ __launch_bounds__(256)
void k_cand_cols(const float* __restrict__ candV, const int* __restrict__ candI,
                 int* __restrict__ candOut) {
  const int t = threadIdx.x;
  const int colLocal = t >> 2;          // 0..63
  const int part = t & 3;               // 0..3
  const int col = blockIdx.x * 64 + colLocal;

  float v[16]; int id[16];
#pragma unroll
  for (int i = 0; i < 16; ++i) { v[i] = -1e30f; id[i] = -1; }

  const size_t cbase = ((size_t)col * COL_CHUNKS + part * 16) * 8;
  for (int c = 0; c < 16; ++c) {
    const float4* pv = (const float4*)(candV + cbase + c * 8);
    const int4*   pi = (const int4*)(candI + cbase + c * 8);
    const float4 a = pv[0], b = pv[1];
    const int4  ia = pi[0], ib = pi[1];
    topk_insert<16>(v, id, a.x, ia.x);
    topk_insert<16>(v, id, a.y, ia.y);
    topk_insert<16>(v, id, a.z, ia.z);
    topk_insert<16>(v, id, a.w, ia.w);
    topk_insert<16>(v, id, b.x, ib.x);
    topk_insert<16>(v, id, b.y, ib.y);
    topk_insert<16>(v, id, b.z, ib.z);
    topk_insert<16>(v, id, b.w, ib.w);
  }

  __shared__ float lv[64][65];   // +1 pad: avoid 16-way bank conflict
  __shared__ int   li[64][65];
#pragma unroll
  for (int i = 0; i < 16; ++i) { lv[colLocal][part * 16 + i] = v[i]; li[colLocal][part * 16 + i] = id[i]; }
  __syncthreads();

#pragma unroll
  for (int i = 0; i < 16; ++i) {
    const float mv = v[i]; const int mi = id[i];
    int rk = 0;
    for (int q = 0; q < 64; ++q) {
      const float qv = lv[colLocal][q]; const int qi = li[colLocal][q];
      rk += (qv > mv || (qv == mv && qi < mi)) ? 1 : 0;
    }
    if (rk < 16) candOut[col * 16 + rk] = mi;
  }
}

// ---------------- exact fp64 rescore of 16 candidates -> top-8 + softmax ----------------
__global__ __launch_bounds__(256)
void k_rescore(const float* __restrict__ Xq, const float* __restrict__ Xc,
               const double* __restrict__ nQ, const double* __restrict__ nC,
               const int* __restrict__ cand, int* __restrict__ idxOut,
               float* __restrict__ wOut) {
  const int r = blockIdx.x;
  const int t = threadIdx.x;
  __shared__ float q[DIM];
  __shared__ double sc[16];
  __shared__ int sidx[16];
  const float2 qv = ((const float2*)(Xq + (size_t)r * DIM))[t];
  q[2 * t] = qv.x; q[2 * t + 1] = qv.y;
  if (t < 16) sidx[t] = cand[r * 16 + t];
  __syncthreads();
  const int wave = t >> 6, lane = t & 63;
  for (int c = wave; c < 16; c += 4) {
    const float* xr = Xc + (size_t)sidx[c] * DIM;
    double acc = 0.0;
    for (int j = lane; j < DIM; j += 64) acc += (double)q[j] * (double)xr[j];
#pragma unroll
    for (int o = 32; o; o >>= 1) acc += __shfl_down(acc, o, 64);
    if (lane == 0) sc[c] = acc;
  }
  __syncthreads();
  if (t == 0) {
    const double nq = nQ[r];
    double s[16]; int id[16];
#pragma unroll
    for (int i = 0; i < 16; ++i) {
      id[i] = sidx[i];
      s[i] = sc[i] / (nq * nC[sidx[i]]) * 5.0;   // /tau, tau=0.2
    }
    // insertion sort: descending score, ascending index on ties
    for (int i = 1; i < 16; ++i) {
      double sv = s[i]; int iv = id[i]; int j = i - 1;
      while (j >= 0 && (s[j] < sv || (s[j] == sv && id[j] > iv))) {
        s[j + 1] = s[j]; id[j + 1] = id[j]; --j;
      }
      s[j + 1] = sv; id[j + 1] = iv;
    }
    double m = s[0], e[8], sum = 0.0;
#pragma unroll
    for (int i = 0; i < 8; ++i) { e[i] = exp(s[i] - m); sum += e[i]; }
    const double inv = 1.0 / sum;
#pragma unroll
    for (int i = 0; i < 8; ++i) {
      idxOut[r * 8 + i] = id[i];
      wOut[r * 8 + i] = (float)(e[i] * inv);
    }
  }
}

// ---------------- gather message + residual + LayerNorm ----------------
__global__ __launch_bounds__(256)
void k_msg_ln(const float* __restrict__ g, const float* __restrict__ P,
              const int* __restrict__ idx, const float* __restrict__ w,
              const float* __restrict__ gamma, const float* __restrict__ beta,
              float* __restrict__ out) {
  const int row = blockIdx.x;
  const int t = threadIdx.x;                  // 256 threads, 2 elems each
  __shared__ int sidx[8];
  __shared__ float sw[8];
  if (t < 8) { sidx[t] = idx[row * 8 + t]; sw[t] = w[row * 8 + t]; }
  __syncthreads();
  float mx = 0.f, my = 0.f;
#pragma unroll
  for (int k = 0; k < 8; ++k) {
    const float2 pv = ((const float2*)(P + (size_t)sidx[k] * DIM))[t];
    mx += sw[k] * pv.x; my += sw[k] * pv.y;
  }
  const float2 gv = ((const float2*)(g + (size_t)row * DIM))[t];
  const float x0 = gv.x + 0.3f * mx;
  const float x1 = gv.y + 0.3f * my;
  float s = x0 + x1, ss = x0 * x0 + x1 * x1;
#pragma unroll
  for (int o = 32; o; o >>= 1) { s += __shfl_down(s, o, 64); ss += __shfl_down(ss, o, 64); }
  __shared__ float ls[4], lss[4];
  if ((t & 63) == 0) { ls[t >> 6] = s; lss[t >> 6] = ss; }
  __syncthreads();
  const float tot = ls[0] + ls[1] + ls[2] + ls[3];
  const float tots = lss[0] + lss[1] + lss[2] + lss[3];
  const float mu = tot * (1.0f / DIM);
  const float var = tots * (1.0f / DIM) - mu * mu;
  const float rstd = rsqrtf(var + 1e-5f);
  const float2 gm = ((const float2*)gamma)[t];
  const float2 bt = ((const float2*)beta)[t];
  float2 o2;
  o2.x = (x0 - mu) * rstd * gm.x + bt.x;
  o2.y = (x1 - mu) * rstd * gm.y + bt.y;
  ((float2*)(out + (size_t)row * DIM))[t] = o2;
}

extern "C" void kernel_launch(void* const* d_in, const int* in_sizes, int n_in,
                              void* d_out, int out_size, void* d_ws, size_t ws_size,
                              hipStream_t stream) {
  const float* gI = (const float*)d_in[0];
  const float* gT = (const float*)d_in[1];
  const float* Wi = (const float*)d_in[2];
  const float* Wt = (const float*)d_in[3];
  const float* gamma_i = (const float*)d_in[4];
  const float* beta_i  = (const float*)d_in[5];
  const float* gamma_t = (const float*)d_in[6];
  const float* beta_t  = (const float*)d_in[7];

  float* outI = (float*)d_out;
  float* outT = outI + (size_t)NB * DIM;
  float* S    = outT + (size_t)NB * DIM;

  // workspace carve-up (byte cursor, 16B aligned)
  char* wsb = (char*)d_ws;
  size_t off = 0;
  auto alloc = [&](size_t bytes) -> void* {
    off = (off + 15) & ~(size_t)15;
    void* p = wsb + off;
    off += bytes;
    return p;
  };
  unsigned short* gIb = (unsigned short*)alloc((size_t)NB * DIM * 2);
  unsigned short* gTb = (unsigned short*)alloc((size_t)NB * DIM * 2);
  unsigned short* Wib = (unsigned short*)alloc((size_t)DIM * DIM * 2);
  unsigned short* Wtb = (unsigned short*)alloc((size_t)DIM * DIM * 2);
  float* rinvI = (float*)alloc((size_t)NB * 4);
  float* rinvT = (float*)alloc((size_t)NB * 4);
  double* normI = (double*)alloc((size_t)NB * 8);
  double* normT = (double*)alloc((size_t)NB * 8);
  float* Pt = (float*)alloc((size_t)NB * DIM * 4);
  float* Pi = (float*)alloc((size_t)NB * DIM * 4);
  float* candV = (float*)alloc((size_t)NB * COL_CHUNKS * 8 * 4);
  int*   candI = (int*)alloc((size_t)NB * COL_CHUNKS * 8 * 4);
  int*   candRow = (int*)alloc((size_t)NB * 16 * 4);
  int*   candCol = (int*)alloc((size_t)NB * 16 * 4);
  int*   idx_it = (int*)alloc((size_t)NB * 8 * 4);
  float* w_it   = (float*)alloc((size_t)NB * 8 * 4);
  int*   idx_ti = (int*)alloc((size_t)NB * 8 * 4);
  float* w_ti   = (float*)alloc((size_t)NB * 8 * 4);

  k_prep<<<NB, 256, 0, stream>>>(gI, gIb, rinvI, normI);
  k_prep<<<NB, 256, 0, stream>>>(gT, gTb, rinvT, normT);
  k_cast<<<(DIM * DIM / 2 + 255) / 256, 256, 0, stream>>>(Wi, Wib, DIM * DIM / 2);
  k_cast<<<(DIM * DIM / 2 + 255) / 256, 256, 0, stream>>>(Wt, Wtb, DIM * DIM / 2);

  // S = (gi . gt^T)/tau, scaled in epilogue by rinvI[i]*rinvT[j]*5
  k_gemm_bt<true><<<dim3(NB / 128, NB / 128), 256, 0, stream>>>(
      gIb, gTb, S, NB, NB, DIM, rinvI, rinvT, 5.0f);
  // Pt = gT @ Wt^T ; Pi = gI @ Wi^T
  k_gemm_bt<false><<<dim3(DIM / 128, NB / 128), 256, 0, stream>>>(
      gTb, Wtb, Pt, NB, DIM, DIM, nullptr, nullptr, 1.0f);
  k_gemm_bt<false><<<dim3(DIM / 128, NB / 128), 256, 0, stream>>>(
      gIb, Wib, Pi, NB, DIM, DIM, nullptr, nullptr, 1.0f);

  // candidates from S
  k_cand_rows<<<NB, 256, 0, stream>>>(S, candRow);
  k_topk_cols_part<<<dim3(NB / 256, COL_CHUNKS), 256, 0, stream>>>(S, candV, candI);
  k_cand_cols<<<NB / 64, 256, 0, stream>>>(candV, candI, candCol);

  // exact fp64 rescore -> final top-8 + weights
  k_rescore<<<NB, 256, 0, stream>>>(gI, gT, normI, normT, candRow, idx_it, w_it);
  k_rescore<<<NB, 256, 0, stream>>>(gT, gI, normT, normI, candCol, idx_ti, w_ti);

  k_msg_ln<<<NB, 256, 0, stream>>>(gI, Pt, idx_it, w_it, gamma_i, beta_i, outI);
  k_msg_ln<<<NB, 256, 0, stream>>>(gT, Pi, idx_ti, w_ti, gamma_t, beta_t, outT);
}